// Round 6
// baseline (626.292 us; speedup 1.0000x reference)
//
#include <hip/hip_runtime.h>
#include <cmath>

// AttentionBlock: GroupNorm -> QKV 1x1 -> 8-head attention (L=1024) -> proj -> residual
// B=16, C=512, L=1024, 32 groups, 8 heads (ch=64). fp32 in/out, bf16 MFMA internally.

#define BATCH 16
#define CDIM 512
#define LDIM 1024

typedef unsigned short u16;
typedef u16 ushort8v __attribute__((ext_vector_type(8)));
typedef __bf16 bf16x8_t __attribute__((ext_vector_type(8)));
typedef float f32x4 __attribute__((ext_vector_type(4)));

__device__ __forceinline__ u16 f2bf(float f) {
  unsigned u = __float_as_uint(f);
  unsigned r = u + 0x7fffu + ((u >> 16) & 1u);  // RNE
  return (u16)(r >> 16);
}
__device__ __forceinline__ unsigned pack2(float a, float b) {
  return (unsigned)f2bf(a) | ((unsigned)f2bf(b) << 16);
}
// truncating bf16 pack: [hi16(a) | hi16(b)<<16] in one v_perm_b32
__device__ __forceinline__ unsigned pack2t(float a, float b) {
  return __builtin_amdgcn_perm(__float_as_uint(b), __float_as_uint(a), 0x07060302u);
}
// truncate to bf16 value (numerator-consistent denominator terms)
__device__ __forceinline__ float bftrunc(float x) {
  return __uint_as_float(__float_as_uint(x) & 0xffff0000u);
}
__device__ __forceinline__ float fast_exp2(float x) {
#if __has_builtin(__builtin_amdgcn_exp2f)
  return __builtin_amdgcn_exp2f(x);  // v_exp_f32 = 2^x
#else
  return exp2f(x);
#endif
}
__device__ __forceinline__ f32x4 mfma16(ushort8v a, ushort8v b, f32x4 c) {
  return __builtin_amdgcn_mfma_f32_16x16x32_bf16(
      __builtin_bit_cast(bf16x8_t, a), __builtin_bit_cast(bf16x8_t, b), c, 0, 0, 0);
}

// ---------------- GroupNorm stats: per-(b,c) scale/shift ----------------
__global__ __launch_bounds__(256) void gn_stats_kernel(const float* __restrict__ x,
                                                       const float* __restrict__ w,
                                                       const float* __restrict__ bvec,
                                                       float* __restrict__ scl,
                                                       float* __restrict__ sh) {
  int bg = blockIdx.x;
  int bb = bg >> 5, g = bg & 31;
  size_t base = ((size_t)bb * CDIM + g * 16) * LDIM;
  const float4* x4 = (const float4*)(x + base);
  int tid = threadIdx.x;
  float sum = 0.f, ss = 0.f;
#pragma unroll
  for (int i = 0; i < 16; ++i) {
    float4 v = x4[tid + 256 * i];
    sum += v.x + v.y + v.z + v.w;
    ss += v.x * v.x + v.y * v.y + v.z * v.z + v.w * v.w;
  }
#pragma unroll
  for (int off = 32; off; off >>= 1) {
    sum += __shfl_xor(sum, off);
    ss += __shfl_xor(ss, off);
  }
  __shared__ float rs[4], rq[4];
  int lane = tid & 63, wv = tid >> 6;
  if (lane == 0) { rs[wv] = sum; rq[wv] = ss; }
  __syncthreads();
  sum = rs[0] + rs[1] + rs[2] + rs[3];
  ss = rq[0] + rq[1] + rq[2] + rq[3];
  const float inv_n = 1.f / (16.f * 1024.f);
  float mean = sum * inv_n;
  float var = ss * inv_n - mean * mean;
  float rstd = rsqrtf(var + 1e-4f);
  if (tid < 16) {
    int c = g * 16 + tid;
    float s = w[c] * rstd;
    scl[bb * CDIM + c] = s;
    sh[bb * CDIM + c] = bvec[c] - mean * s;
  }
}

// ---------------- MFMA GEMM, 128x128 tile, BK=32 ----------------
// MODE 0: QK rows -> transposed output qt/kt[bh][t][c] bf16 (Q scaled by 0.125*log2e)
// MODE 1: V rows  -> v[b][c][l] bf16
// MODE 2: proj    -> fp32 out + bias + residual (B input = av bf16)
template <int MODE>
__global__ __launch_bounds__(256) void gemm_mfma(
    const float* __restrict__ Wg, const float* __restrict__ biasg,
    const float* __restrict__ Xf, const u16* __restrict__ Xb,
    const float* __restrict__ scl, const float* __restrict__ sh,
    const float* __restrict__ resid,
    u16* __restrict__ qo, u16* __restrict__ ko,
    u16* __restrict__ vo, float* __restrict__ fo, int m_base) {
  __shared__ __align__(16) u16 Ws[128][40];  // [m][k], pad 40
  __shared__ __align__(16) u16 Xs[128][40];  // [n][k]
  int bb = blockIdx.z;
  int m0 = m_base + blockIdx.y * 128;
  int n0 = blockIdx.x * 128;
  int tid = threadIdx.x;
  int w = tid >> 6, lane = tid & 63, quad = lane >> 4, l15 = lane & 15;
  int wm = (w >> 1) * 64, wn = (w & 1) * 64;
  f32x4 acc[4][4] = {};  // MODE0: [nsub][msub]; else: [msub][nsub]
  int xkb = tid >> 5, xnb = tid & 31;

  for (int kk = 0; kk < 512; kk += 32) {
    float4 wv[4];
#pragma unroll
    for (int r = 0; r < 4; ++r) {
      int f = tid + 256 * r;
      wv[r] = *(const float4*)&Wg[(size_t)(m0 + (f >> 3)) * 512 + kk + (f & 7) * 4];
    }
    uint2 xw[4];
    if (MODE != 2) {
      float4 xv[4];
#pragma unroll
      for (int r = 0; r < 4; ++r) {
        int kch = kk + xkb * 4 + r;
        float s_ = scl[bb * CDIM + kch];
        float h_ = sh[bb * CDIM + kch];
        float4 t = *(const float4*)&Xf[((size_t)bb * CDIM + kch) * LDIM + n0 + xnb * 4];
        xv[r] = make_float4(t.x * s_ + h_, t.y * s_ + h_, t.z * s_ + h_, t.w * s_ + h_);
      }
#pragma unroll
      for (int j = 0; j < 4; ++j) {
        const float* p0 = (const float*)&xv[0];
        const float* p1 = (const float*)&xv[1];
        const float* p2 = (const float*)&xv[2];
        const float* p3 = (const float*)&xv[3];
        xw[j].x = pack2(p0[j], p1[j]);
        xw[j].y = pack2(p2[j], p3[j]);
      }
    } else {
      ushort4 xu[4];
#pragma unroll
      for (int r = 0; r < 4; ++r)
        xu[r] = *(const ushort4*)&Xb[((size_t)bb * CDIM + kk + xkb * 4 + r) * LDIM + n0 + xnb * 4];
#pragma unroll
      for (int j = 0; j < 4; ++j) {
        const u16* p0 = (const u16*)&xu[0];
        const u16* p1 = (const u16*)&xu[1];
        const u16* p2 = (const u16*)&xu[2];
        const u16* p3 = (const u16*)&xu[3];
        xw[j].x = (unsigned)p0[j] | ((unsigned)p1[j] << 16);
        xw[j].y = (unsigned)p2[j] | ((unsigned)p3[j] << 16);
      }
    }
    __syncthreads();
#pragma unroll
    for (int r = 0; r < 4; ++r) {
      int f = tid + 256 * r;
      uint2 u;
      u.x = pack2(wv[r].x, wv[r].y);
      u.y = pack2(wv[r].z, wv[r].w);
      *(uint2*)&Ws[f >> 3][(f & 7) * 4] = u;
    }
#pragma unroll
    for (int j = 0; j < 4; ++j) *(uint2*)&Xs[xnb * 4 + j][xkb * 4] = xw[j];
    __syncthreads();
    ushort8v af[4], bfr[4];
#pragma unroll
    for (int i = 0; i < 4; ++i) af[i] = *(const ushort8v*)&Ws[wm + i * 16 + l15][quad * 8];
#pragma unroll
    for (int i = 0; i < 4; ++i) bfr[i] = *(const ushort8v*)&Xs[wn + i * 16 + l15][quad * 8];
#pragma unroll
    for (int i = 0; i < 4; ++i)
#pragma unroll
      for (int j = 0; j < 4; ++j) {
        if (MODE == 0)
          acc[j][i] = mfma16(bfr[j], af[i], acc[j][i]);  // D[n][m]
        else
          acc[i][j] = mfma16(af[i], bfr[j], acc[i][j]);  // D[m][n]
      }
  }

  if (MODE == 0) {
    bool isQ = (m0 < 512);
    // log2e folded into Q so attention can use raw v_exp_f32 (2^x)
    float qscale = isQ ? (0.125f * 1.44269504f) : 1.0f;
    u16* dst = isQ ? qo : ko;
    int cbase0 = m0 - (isQ ? 0 : 512) + wm;
#pragma unroll
    for (int i = 0; i < 4; ++i) {
      int cg = cbase0 + i * 16 + l15;
      float bv = biasg[m0 + wm + i * 16 + l15];
      int hh = cg >> 6, cl = cg & 63;
      size_t rowbase = ((size_t)(bb * 8 + hh) * 1024) * 64 + cl;
#pragma unroll
      for (int j = 0; j < 4; ++j)
#pragma unroll
        for (int r = 0; r < 4; ++r) {
          int t = n0 + wn + j * 16 + quad * 4 + r;
          dst[rowbase + (size_t)t * 64] = f2bf((acc[j][i][r] + bv) * qscale);
        }
    }
  } else if (MODE == 1) {
#pragma unroll
    for (int i = 0; i < 4; ++i)
#pragma unroll
      for (int r = 0; r < 4; ++r) {
        int m_abs = m0 + wm + i * 16 + quad * 4 + r;
        float bv = biasg[m_abs];
        int cg = m_abs - 1024;
#pragma unroll
        for (int j = 0; j < 4; ++j) {
          int n = n0 + wn + j * 16 + l15;
          vo[((size_t)bb * CDIM + cg) * LDIM + n] = f2bf(acc[i][j][r] + bv);
        }
      }
  } else {
#pragma unroll
    for (int i = 0; i < 4; ++i)
#pragma unroll
      for (int r = 0; r < 4; ++r) {
        int m_abs = m0 + wm + i * 16 + quad * 4 + r;
        float bv = biasg[m_abs];
#pragma unroll
        for (int j = 0; j < 4; ++j) {
          int n = n0 + wn + j * 16 + l15;
          size_t off = ((size_t)bb * CDIM + m_abs) * LDIM + n;
          fo[off] = acc[i][j][r] + bv + resid[off];
        }
      }
  }
}

// ---------------- Attention, MFMA, no-max softmax, split-s, XCD-local ----------------
// Grid (128 bh, 16 t-blocks): linear id % 8 == bh % 8 -> all 16 blocks of a head
// land on one XCD -> K/V (256 KB/head) L2-resident.
// Block: 4 waves = 2 t-groups x 2 s-halves. Wave: 32 t x 512 s (16 s-tiles of 32).
// No-max softmax makes split-s exact: partial num/denom just add (2 LDS rounds).
// Q pre-scaled by 0.125*log2e -> p = v_exp_f32(score). Ps wave-private, no
// barriers in the loop. K prefetched 1 tile ahead; V issued early.
__global__ __launch_bounds__(256, 8) void attn_mfma(const u16* __restrict__ qt,
                                                    const u16* __restrict__ kt,
                                                    const u16* __restrict__ vv,
                                                    u16* __restrict__ av_out) {
  __shared__ __align__(16) u16 Ps[4][32][40];  // per-wave P tile [t][s], 10 KB
  __shared__ float Cb[2][64][18];              // wave-pair combine, 9 KB
  int bh = blockIdx.x;
  int t0b = blockIdx.y * 64;
  int b = bh >> 3, h = bh & 7;
  int tid = threadIdx.x;
  int w = tid >> 6, lane = tid & 63, quad = lane >> 4, l15 = lane & 15;
  int tg = w >> 1, shalf = w & 1;
  int t0w = t0b + tg * 32;
  int sbeg = shalf * 512;
  size_t head = (size_t)bh * 65536;  // 1024*64
  const u16* kbase = kt + head;
  const u16* vbase = vv + head;

  ushort8v qf[2][2];
#pragma unroll
  for (int ts = 0; ts < 2; ++ts)
#pragma unroll
    for (int kc = 0; kc < 2; ++kc)
      qf[ts][kc] =
          *(const ushort8v*)&qt[head + (size_t)(t0w + ts * 16 + l15) * 64 + kc * 32 + quad * 8];

  f32x4 Co[4][2] = {};
  float lacc[2] = {0.f, 0.f};

  // prefetch first K tile of this wave's s-half
  ushort8v kf[2][2];
#pragma unroll
  for (int ms = 0; ms < 2; ++ms)
#pragma unroll
    for (int kc = 0; kc < 2; ++kc)
      kf[ms][kc] =
          *(const ushort8v*)&kbase[(size_t)(sbeg + ms * 16 + l15) * 64 + kc * 32 + quad * 8];

  for (int si = 0; si < 512; si += 32) {
    int s0 = sbeg + si;
    // V for this tile: issued early, consumed later by PV
    ushort8v vf[4];
#pragma unroll
    for (int cs = 0; cs < 4; ++cs)
      vf[cs] = *(const ushort8v*)&vbase[(size_t)(cs * 16 + l15) * 1024 + s0 + quad * 8];

    // QK^T -> S^T tile (rows=s, cols=t); consumes current kf
    f32x4 st[2][2];
#pragma unroll
    for (int ts = 0; ts < 2; ++ts)
#pragma unroll
      for (int ms = 0; ms < 2; ++ms) {
        f32x4 z = {};
        z = mfma16(kf[ms][0], qf[ts][0], z);
        st[ts][ms] = mfma16(kf[ms][1], qf[ts][1], z);
      }

    // prefetch K for next tile (wrap inside this s-half; last reload unused)
    int sn = sbeg + ((si + 32) & 511);
#pragma unroll
    for (int ms = 0; ms < 2; ++ms)
#pragma unroll
      for (int kc = 0; kc < 2; ++kc)
        kf[ms][kc] =
            *(const ushort8v*)&kbase[(size_t)(sn + ms * 16 + l15) * 64 + kc * 32 + quad * 8];

    // exp2, truncate-consistent denominator, pack, wave-private LDS
#pragma unroll
    for (int ts = 0; ts < 2; ++ts) {
      float p0 = fast_exp2(st[ts][0].x), p1 = fast_exp2(st[ts][0].y);
      float p2 = fast_exp2(st[ts][0].z), p3 = fast_exp2(st[ts][0].w);
      float p4 = fast_exp2(st[ts][1].x), p5 = fast_exp2(st[ts][1].y);
      float p6 = fast_exp2(st[ts][1].z), p7 = fast_exp2(st[ts][1].w);
      lacc[ts] += ((bftrunc(p0) + bftrunc(p1)) + (bftrunc(p2) + bftrunc(p3))) +
                  ((bftrunc(p4) + bftrunc(p5)) + (bftrunc(p6) + bftrunc(p7)));
      uint2 u0, u1;
      u0.x = pack2t(p0, p1);
      u0.y = pack2t(p2, p3);
      u1.x = pack2t(p4, p5);
      u1.y = pack2t(p6, p7);
      *(uint2*)&Ps[w][ts * 16 + l15][quad * 4] = u0;
      *(uint2*)&Ps[w][ts * 16 + l15][16 + quad * 4] = u1;
    }
    // same-wave LDS RAW: ordered by lgkmcnt, no barrier needed
    ushort8v pb[2];
#pragma unroll
    for (int ts = 0; ts < 2; ++ts) pb[ts] = *(const ushort8v*)&Ps[w][ts * 16 + l15][quad * 8];
#pragma unroll
    for (int cs = 0; cs < 4; ++cs)
#pragma unroll
      for (int ts = 0; ts < 2; ++ts) Co[cs][ts] = mfma16(vf[cs], pb[ts], Co[cs][ts]);
  }

  // intra-wave denominator reduce over quads (lanes share l15=t)
#pragma unroll
  for (int ts = 0; ts < 2; ++ts) {
    lacc[ts] += __shfl_xor(lacc[ts], 16);
    lacc[ts] += __shfl_xor(lacc[ts], 32);
  }

  // wave-pair combine: shalf=1 partials -> shalf=0 (2 rounds through Cb)
  __syncthreads();
  if (shalf == 1) {
#pragma unroll
    for (int cs = 0; cs < 2; ++cs)
#pragma unroll
      for (int ts = 0; ts < 2; ++ts)
#pragma unroll
        for (int r = 0; r < 4; ++r) Cb[tg][lane][cs * 8 + ts * 4 + r] = Co[cs][ts][r];
    Cb[tg][lane][16] = lacc[0];
    Cb[tg][lane][17] = lacc[1];
  }
  __syncthreads();
  if (shalf == 0) {
#pragma unroll
    for (int cs = 0; cs < 2; ++cs)
#pragma unroll
      for (int ts = 0; ts < 2; ++ts)
#pragma unroll
        for (int r = 0; r < 4; ++r) Co[cs][ts][r] += Cb[tg][lane][cs * 8 + ts * 4 + r];
    lacc[0] += Cb[tg][lane][16];
    lacc[1] += Cb[tg][lane][17];
  }
  __syncthreads();
  if (shalf == 1) {
#pragma unroll
    for (int cs = 2; cs < 4; ++cs)
#pragma unroll
      for (int ts = 0; ts < 2; ++ts)
#pragma unroll
        for (int r = 0; r < 4; ++r) Cb[tg][lane][(cs - 2) * 8 + ts * 4 + r] = Co[cs][ts][r];
  }
  __syncthreads();
  if (shalf == 0) {
#pragma unroll
    for (int cs = 2; cs < 4; ++cs)
#pragma unroll
      for (int ts = 0; ts < 2; ++ts)
#pragma unroll
        for (int r = 0; r < 4; ++r) Co[cs][ts][r] += Cb[tg][lane][(cs - 2) * 8 + ts * 4 + r];
    float inv[2] = {1.f / lacc[0], 1.f / lacc[1]};
#pragma unroll
    for (int cs = 0; cs < 4; ++cs)
#pragma unroll
      for (int ts = 0; ts < 2; ++ts) {
        int t = t0w + ts * 16 + l15;
#pragma unroll
        for (int r = 0; r < 4; ++r) {
          int c = h * 64 + cs * 16 + quad * 4 + r;
          av_out[((size_t)b * CDIM + c) * LDIM + t] = f2bf(Co[cs][ts][r] * inv[ts]);
        }
      }
  }
}

extern "C" void kernel_launch(void* const* d_in, const int* in_sizes, int n_in,
                              void* d_out, int out_size, void* d_ws, size_t ws_size,
                              hipStream_t stream) {
  const float* x = (const float*)d_in[0];
  const float* norm_w = (const float*)d_in[1];
  const float* norm_b = (const float*)d_in[2];
  const float* qkv_w = (const float*)d_in[3];
  const float* qkv_b = (const float*)d_in[4];
  const float* proj_w = (const float*)d_in[5];
  const float* proj_b = (const float*)d_in[6];
  float* out = (float*)d_out;

  const size_t NE = (size_t)BATCH * CDIM * LDIM;  // 8.39M
  float* scl = (float*)d_ws;
  float* sh = scl + BATCH * CDIM;
  u16* qt = (u16*)(sh + BATCH * CDIM);  // [bh][t][c] bf16
  u16* kt = qt + NE;                    // [bh][s][c] bf16
  u16* vv = kt + NE;                    // [b][c][l]  bf16
  u16* av = vv + NE;                    // [b][c][l]  bf16

  gn_stats_kernel<<<dim3(BATCH * 32), dim3(256), 0, stream>>>(x, norm_w, norm_b, scl, sh);
  gemm_mfma<0><<<dim3(8, 8, BATCH), dim3(256), 0, stream>>>(
      qkv_w, qkv_b, x, (const u16*)nullptr, scl, sh, (const float*)nullptr,
      qt, kt, (u16*)nullptr, (float*)nullptr, 0);
  gemm_mfma<1><<<dim3(8, 4, BATCH), dim3(256), 0, stream>>>(
      qkv_w, qkv_b, x, (const u16*)nullptr, scl, sh, (const float*)nullptr,
      (u16*)nullptr, (u16*)nullptr, vv, (float*)nullptr, 1024);
  attn_mfma<<<dim3(128, 16), dim3(256), 0, stream>>>(qt, kt, vv, av);
  gemm_mfma<2><<<dim3(8, 4, BATCH), dim3(256), 0, stream>>>(
      proj_w, proj_b, (const float*)nullptr, av, (const float*)nullptr, (const float*)nullptr,
      x, (u16*)nullptr, (u16*)nullptr, (u16*)nullptr, out, 0);
}

// Round 7
// 316.805 us; speedup vs baseline: 1.9769x; 1.9769x over previous
//
#include <hip/hip_runtime.h>
#include <cmath>

// AttentionBlock: GroupNorm -> QKV 1x1 -> 8-head attention (L=1024) -> proj -> residual
// B=16, C=512, L=1024, 32 groups, 8 heads (ch=64). fp32 in/out, bf16 MFMA internally.

#define BATCH 16
#define CDIM 512
#define LDIM 1024

typedef unsigned short u16;
typedef u16 ushort8v __attribute__((ext_vector_type(8)));
typedef __bf16 bf16x8_t __attribute__((ext_vector_type(8)));
typedef float f32x4 __attribute__((ext_vector_type(4)));

__device__ __forceinline__ u16 f2bf(float f) {
  unsigned u = __float_as_uint(f);
  unsigned r = u + 0x7fffu + ((u >> 16) & 1u);  // RNE
  return (u16)(r >> 16);
}
__device__ __forceinline__ unsigned pack2(float a, float b) {
  return (unsigned)f2bf(a) | ((unsigned)f2bf(b) << 16);
}
// truncating bf16 pack: [hi16(a) | hi16(b)<<16] in one v_perm_b32
__device__ __forceinline__ unsigned pack2t(float a, float b) {
  return __builtin_amdgcn_perm(__float_as_uint(b), __float_as_uint(a), 0x07060302u);
}
// truncate to bf16 value (numerator-consistent denominator terms)
__device__ __forceinline__ float bftrunc(float x) {
  return __uint_as_float(__float_as_uint(x) & 0xffff0000u);
}
__device__ __forceinline__ float fast_exp2(float x) {
#if __has_builtin(__builtin_amdgcn_exp2f)
  return __builtin_amdgcn_exp2f(x);  // v_exp_f32 = 2^x
#else
  return exp2f(x);
#endif
}
__device__ __forceinline__ f32x4 mfma16(ushort8v a, ushort8v b, f32x4 c) {
  return __builtin_amdgcn_mfma_f32_16x16x32_bf16(
      __builtin_bit_cast(bf16x8_t, a), __builtin_bit_cast(bf16x8_t, b), c, 0, 0, 0);
}

// ---------------- GroupNorm stats: per-(b,c) scale/shift ----------------
__global__ __launch_bounds__(256) void gn_stats_kernel(const float* __restrict__ x,
                                                       const float* __restrict__ w,
                                                       const float* __restrict__ bvec,
                                                       float* __restrict__ scl,
                                                       float* __restrict__ sh) {
  int bg = blockIdx.x;
  int bb = bg >> 5, g = bg & 31;
  size_t base = ((size_t)bb * CDIM + g * 16) * LDIM;
  const float4* x4 = (const float4*)(x + base);
  int tid = threadIdx.x;
  float sum = 0.f, ss = 0.f;
#pragma unroll
  for (int i = 0; i < 16; ++i) {
    float4 v = x4[tid + 256 * i];
    sum += v.x + v.y + v.z + v.w;
    ss += v.x * v.x + v.y * v.y + v.z * v.z + v.w * v.w;
  }
#pragma unroll
  for (int off = 32; off; off >>= 1) {
    sum += __shfl_xor(sum, off);
    ss += __shfl_xor(ss, off);
  }
  __shared__ float rs[4], rq[4];
  int lane = tid & 63, wv = tid >> 6;
  if (lane == 0) { rs[wv] = sum; rq[wv] = ss; }
  __syncthreads();
  sum = rs[0] + rs[1] + rs[2] + rs[3];
  ss = rq[0] + rq[1] + rq[2] + rq[3];
  const float inv_n = 1.f / (16.f * 1024.f);
  float mean = sum * inv_n;
  float var = ss * inv_n - mean * mean;
  float rstd = rsqrtf(var + 1e-4f);
  if (tid < 16) {
    int c = g * 16 + tid;
    float s = w[c] * rstd;
    scl[bb * CDIM + c] = s;
    sh[bb * CDIM + c] = bvec[c] - mean * s;
  }
}

// ---------------- MFMA GEMM, 128x128 tile, BK=32 ----------------
// MODE 0: QK rows -> transposed output qt/kt[bh][t][c] bf16 (Q scaled by 0.125*log2e)
// MODE 1: V rows  -> v[b][c][l] bf16
// MODE 2: proj    -> fp32 out + bias + residual (B input = av bf16)
template <int MODE>
__global__ __launch_bounds__(256) void gemm_mfma(
    const float* __restrict__ Wg, const float* __restrict__ biasg,
    const float* __restrict__ Xf, const u16* __restrict__ Xb,
    const float* __restrict__ scl, const float* __restrict__ sh,
    const float* __restrict__ resid,
    u16* __restrict__ qo, u16* __restrict__ ko,
    u16* __restrict__ vo, float* __restrict__ fo, int m_base) {
  __shared__ __align__(16) u16 Ws[128][40];  // [m][k], pad 40
  __shared__ __align__(16) u16 Xs[128][40];  // [n][k]
  int bb = blockIdx.z;
  int m0 = m_base + blockIdx.y * 128;
  int n0 = blockIdx.x * 128;
  int tid = threadIdx.x;
  int w = tid >> 6, lane = tid & 63, quad = lane >> 4, l15 = lane & 15;
  int wm = (w >> 1) * 64, wn = (w & 1) * 64;
  f32x4 acc[4][4] = {};  // MODE0: [nsub][msub]; else: [msub][nsub]
  int xkb = tid >> 5, xnb = tid & 31;

  for (int kk = 0; kk < 512; kk += 32) {
    float4 wv[4];
#pragma unroll
    for (int r = 0; r < 4; ++r) {
      int f = tid + 256 * r;
      wv[r] = *(const float4*)&Wg[(size_t)(m0 + (f >> 3)) * 512 + kk + (f & 7) * 4];
    }
    uint2 xw[4];
    if (MODE != 2) {
      float4 xv[4];
#pragma unroll
      for (int r = 0; r < 4; ++r) {
        int kch = kk + xkb * 4 + r;
        float s_ = scl[bb * CDIM + kch];
        float h_ = sh[bb * CDIM + kch];
        float4 t = *(const float4*)&Xf[((size_t)bb * CDIM + kch) * LDIM + n0 + xnb * 4];
        xv[r] = make_float4(t.x * s_ + h_, t.y * s_ + h_, t.z * s_ + h_, t.w * s_ + h_);
      }
#pragma unroll
      for (int j = 0; j < 4; ++j) {
        const float* p0 = (const float*)&xv[0];
        const float* p1 = (const float*)&xv[1];
        const float* p2 = (const float*)&xv[2];
        const float* p3 = (const float*)&xv[3];
        xw[j].x = pack2(p0[j], p1[j]);
        xw[j].y = pack2(p2[j], p3[j]);
      }
    } else {
      ushort4 xu[4];
#pragma unroll
      for (int r = 0; r < 4; ++r)
        xu[r] = *(const ushort4*)&Xb[((size_t)bb * CDIM + kk + xkb * 4 + r) * LDIM + n0 + xnb * 4];
#pragma unroll
      for (int j = 0; j < 4; ++j) {
        const u16* p0 = (const u16*)&xu[0];
        const u16* p1 = (const u16*)&xu[1];
        const u16* p2 = (const u16*)&xu[2];
        const u16* p3 = (const u16*)&xu[3];
        xw[j].x = (unsigned)p0[j] | ((unsigned)p1[j] << 16);
        xw[j].y = (unsigned)p2[j] | ((unsigned)p3[j] << 16);
      }
    }
    __syncthreads();
#pragma unroll
    for (int r = 0; r < 4; ++r) {
      int f = tid + 256 * r;
      uint2 u;
      u.x = pack2(wv[r].x, wv[r].y);
      u.y = pack2(wv[r].z, wv[r].w);
      *(uint2*)&Ws[f >> 3][(f & 7) * 4] = u;
    }
#pragma unroll
    for (int j = 0; j < 4; ++j) *(uint2*)&Xs[xnb * 4 + j][xkb * 4] = xw[j];
    __syncthreads();
    ushort8v af[4], bfr[4];
#pragma unroll
    for (int i = 0; i < 4; ++i) af[i] = *(const ushort8v*)&Ws[wm + i * 16 + l15][quad * 8];
#pragma unroll
    for (int i = 0; i < 4; ++i) bfr[i] = *(const ushort8v*)&Xs[wn + i * 16 + l15][quad * 8];
#pragma unroll
    for (int i = 0; i < 4; ++i)
#pragma unroll
      for (int j = 0; j < 4; ++j) {
        if (MODE == 0)
          acc[j][i] = mfma16(bfr[j], af[i], acc[j][i]);  // D[n][m]
        else
          acc[i][j] = mfma16(af[i], bfr[j], acc[i][j]);  // D[m][n]
      }
  }

  if (MODE == 0) {
    bool isQ = (m0 < 512);
    // log2e folded into Q so attention can use raw v_exp_f32 (2^x)
    float qscale = isQ ? (0.125f * 1.44269504f) : 1.0f;
    u16* dst = isQ ? qo : ko;
    int cbase0 = m0 - (isQ ? 0 : 512) + wm;
#pragma unroll
    for (int i = 0; i < 4; ++i) {
      int cg = cbase0 + i * 16 + l15;
      float bv = biasg[m0 + wm + i * 16 + l15];
      int hh = cg >> 6, cl = cg & 63;
      size_t rowbase = ((size_t)(bb * 8 + hh) * 1024) * 64 + cl;
#pragma unroll
      for (int j = 0; j < 4; ++j)
#pragma unroll
        for (int r = 0; r < 4; ++r) {
          int t = n0 + wn + j * 16 + quad * 4 + r;
          dst[rowbase + (size_t)t * 64] = f2bf((acc[j][i][r] + bv) * qscale);
        }
    }
  } else if (MODE == 1) {
#pragma unroll
    for (int i = 0; i < 4; ++i)
#pragma unroll
      for (int r = 0; r < 4; ++r) {
        int m_abs = m0 + wm + i * 16 + quad * 4 + r;
        float bv = biasg[m_abs];
        int cg = m_abs - 1024;
#pragma unroll
        for (int j = 0; j < 4; ++j) {
          int n = n0 + wn + j * 16 + l15;
          vo[((size_t)bb * CDIM + cg) * LDIM + n] = f2bf(acc[i][j][r] + bv);
        }
      }
  } else {
#pragma unroll
    for (int i = 0; i < 4; ++i)
#pragma unroll
      for (int r = 0; r < 4; ++r) {
        int m_abs = m0 + wm + i * 16 + quad * 4 + r;
        float bv = biasg[m_abs];
#pragma unroll
        for (int j = 0; j < 4; ++j) {
          int n = n0 + wn + j * 16 + l15;
          size_t off = ((size_t)bb * CDIM + m_abs) * LDIM + n;
          fo[off] = acc[i][j][r] + bv + resid[off];
        }
      }
  }
}

// ---------------- Attention, MFMA, no-max softmax, K+V rotated prefetch ----------------
// Grid (bh=128, tblk=8): linear id = bh + 128*tblk => id%8 == bh%8 -> all 8
// t-blocks of one head land on one XCD -> per-head K/V (256 KB) L2-resident.
// Block: 4 waves x 32 t, one bh; s-tiles of 32. Q pre-scaled by 0.125*log2e:
// p = v_exp_f32(score). Denominator = per-lane sums of TRUNCATED p, 2 shuffles
// at loop end. BOTH K and V are prefetched one full tile ahead: kf(i+1) loads
// right after QK consumes kf(i); vf(i+1) right after PV consumes vf(i) --
// register-neutral rotation, full-iteration latency cover for both streams.
// Ps is wave-private -> no barriers anywhere in the loop.
__global__ __launch_bounds__(256, 4) void attn_mfma(const u16* __restrict__ qt,
                                                    const u16* __restrict__ kt,
                                                    const u16* __restrict__ vv,
                                                    u16* __restrict__ av_out) {
  __shared__ __align__(16) u16 Ps[4][32][40];  // per-wave P tile [t][s], pad 40
  int bh = blockIdx.x;
  int t0b = blockIdx.y * 128;
  int b = bh >> 3, h = bh & 7;
  int tid = threadIdx.x;
  int w = tid >> 6, lane = tid & 63, quad = lane >> 4, l15 = lane & 15;
  int t0w = t0b + w * 32;
  size_t head = (size_t)bh * 65536;  // 1024*64
  const u16* kbase = kt + head;
  const u16* vbase = vv + head;

  ushort8v qf[2][2];
#pragma unroll
  for (int ts = 0; ts < 2; ++ts)
#pragma unroll
    for (int kc = 0; kc < 2; ++kc)
      qf[ts][kc] =
          *(const ushort8v*)&qt[head + (size_t)(t0w + ts * 16 + l15) * 64 + kc * 32 + quad * 8];

  f32x4 Co[4][2] = {};
  float lacc[2] = {0.f, 0.f};

  // prefetch K tile 0 and V tile 0
  ushort8v kf[2][2];
#pragma unroll
  for (int ms = 0; ms < 2; ++ms)
#pragma unroll
    for (int kc = 0; kc < 2; ++kc)
      kf[ms][kc] = *(const ushort8v*)&kbase[(size_t)(ms * 16 + l15) * 64 + kc * 32 + quad * 8];
  ushort8v vf[4];
#pragma unroll
  for (int cs = 0; cs < 4; ++cs)
    vf[cs] = *(const ushort8v*)&vbase[(size_t)(cs * 16 + l15) * 1024 + quad * 8];

  for (int s0 = 0; s0 < 1024; s0 += 32) {
    // QK^T -> S^T tile (rows=s, cols=t); consumes current kf
    f32x4 st[2][2];
#pragma unroll
    for (int ts = 0; ts < 2; ++ts)
#pragma unroll
      for (int ms = 0; ms < 2; ++ms) {
        f32x4 z = {};
        z = mfma16(kf[ms][0], qf[ts][0], z);
        st[ts][ms] = mfma16(kf[ms][1], qf[ts][1], z);
      }

    // prefetch K for next tile (wrap: last iteration reloads tile 0, unused)
    int sn = (s0 + 32) & 1023;
#pragma unroll
    for (int ms = 0; ms < 2; ++ms)
#pragma unroll
      for (int kc = 0; kc < 2; ++kc)
        kf[ms][kc] =
            *(const ushort8v*)&kbase[(size_t)(sn + ms * 16 + l15) * 64 + kc * 32 + quad * 8];

    // exp2, truncate-consistent denominator, pack, wave-private LDS
#pragma unroll
    for (int ts = 0; ts < 2; ++ts) {
      float p0 = fast_exp2(st[ts][0].x), p1 = fast_exp2(st[ts][0].y);
      float p2 = fast_exp2(st[ts][0].z), p3 = fast_exp2(st[ts][0].w);
      float p4 = fast_exp2(st[ts][1].x), p5 = fast_exp2(st[ts][1].y);
      float p6 = fast_exp2(st[ts][1].z), p7 = fast_exp2(st[ts][1].w);
      lacc[ts] += ((bftrunc(p0) + bftrunc(p1)) + (bftrunc(p2) + bftrunc(p3))) +
                  ((bftrunc(p4) + bftrunc(p5)) + (bftrunc(p6) + bftrunc(p7)));
      uint2 u0, u1;
      u0.x = pack2t(p0, p1);
      u0.y = pack2t(p2, p3);
      u1.x = pack2t(p4, p5);
      u1.y = pack2t(p6, p7);
      *(uint2*)&Ps[w][ts * 16 + l15][quad * 4] = u0;
      *(uint2*)&Ps[w][ts * 16 + l15][16 + quad * 4] = u1;
    }
    // same-wave LDS RAW: ordered by lgkmcnt, no barrier needed
    ushort8v pb[2];
#pragma unroll
    for (int ts = 0; ts < 2; ++ts) pb[ts] = *(const ushort8v*)&Ps[w][ts * 16 + l15][quad * 8];
    // PV consumes current vf
#pragma unroll
    for (int cs = 0; cs < 4; ++cs)
#pragma unroll
      for (int ts = 0; ts < 2; ++ts) Co[cs][ts] = mfma16(vf[cs], pb[ts], Co[cs][ts]);
    // prefetch V for next tile (registers rotate WAR-clean after PV issue)
#pragma unroll
    for (int cs = 0; cs < 4; ++cs)
      vf[cs] = *(const ushort8v*)&vbase[(size_t)(cs * 16 + l15) * 1024 + sn + quad * 8];
  }

  // denominator: sum over quads (lanes share l15=t)
#pragma unroll
  for (int ts = 0; ts < 2; ++ts) {
    lacc[ts] += __shfl_xor(lacc[ts], 16);
    lacc[ts] += __shfl_xor(lacc[ts], 32);
  }
  float inv[2] = {1.f / lacc[0], 1.f / lacc[1]};
#pragma unroll
  for (int cs = 0; cs < 4; ++cs)
#pragma unroll
    for (int ts = 0; ts < 2; ++ts) {
      int t = t0w + ts * 16 + l15;
#pragma unroll
      for (int r = 0; r < 4; ++r) {
        int c = h * 64 + cs * 16 + quad * 4 + r;
        av_out[((size_t)b * CDIM + c) * LDIM + t] = f2bf(Co[cs][ts][r] * inv[ts]);
      }
    }
}

extern "C" void kernel_launch(void* const* d_in, const int* in_sizes, int n_in,
                              void* d_out, int out_size, void* d_ws, size_t ws_size,
                              hipStream_t stream) {
  const float* x = (const float*)d_in[0];
  const float* norm_w = (const float*)d_in[1];
  const float* norm_b = (const float*)d_in[2];
  const float* qkv_w = (const float*)d_in[3];
  const float* qkv_b = (const float*)d_in[4];
  const float* proj_w = (const float*)d_in[5];
  const float* proj_b = (const float*)d_in[6];
  float* out = (float*)d_out;

  const size_t NE = (size_t)BATCH * CDIM * LDIM;  // 8.39M
  float* scl = (float*)d_ws;
  float* sh = scl + BATCH * CDIM;
  u16* qt = (u16*)(sh + BATCH * CDIM);  // [bh][t][c] bf16
  u16* kt = qt + NE;                    // [bh][s][c] bf16
  u16* vv = kt + NE;                    // [b][c][l]  bf16
  u16* av = vv + NE;                    // [b][c][l]  bf16

  gn_stats_kernel<<<dim3(BATCH * 32), dim3(256), 0, stream>>>(x, norm_w, norm_b, scl, sh);
  gemm_mfma<0><<<dim3(8, 8, BATCH), dim3(256), 0, stream>>>(
      qkv_w, qkv_b, x, (const u16*)nullptr, scl, sh, (const float*)nullptr,
      qt, kt, (u16*)nullptr, (float*)nullptr, 0);
  gemm_mfma<1><<<dim3(8, 4, BATCH), dim3(256), 0, stream>>>(
      qkv_w, qkv_b, x, (const u16*)nullptr, scl, sh, (const float*)nullptr,
      (u16*)nullptr, (u16*)nullptr, vv, (float*)nullptr, 1024);
  attn_mfma<<<dim3(128, 8), dim3(256), 0, stream>>>(qt, kt, vv, av);
  gemm_mfma<2><<<dim3(8, 4, BATCH), dim3(256), 0, stream>>>(
      proj_w, proj_b, (const float*)nullptr, av, (const float*)nullptr, (const float*)nullptr,
      x, (u16*)nullptr, (u16*)nullptr, (u16*)nullptr, out, 0);
}

// Round 8
// 313.412 us; speedup vs baseline: 1.9983x; 1.0108x over previous
//
#include <hip/hip_runtime.h>
#include <cmath>

// AttentionBlock: GroupNorm -> QKV 1x1 -> 8-head attention (L=1024) -> proj -> residual
// B=16, C=512, L=1024, 32 groups, 8 heads (ch=64). fp32 in/out, bf16 MFMA internally.

#define BATCH 16
#define CDIM 512
#define LDIM 1024

typedef unsigned short u16;
typedef u16 ushort8v __attribute__((ext_vector_type(8)));
typedef __bf16 bf16x8_t __attribute__((ext_vector_type(8)));
typedef float f32x4 __attribute__((ext_vector_type(4)));

__device__ __forceinline__ u16 f2bf(float f) {
  unsigned u = __float_as_uint(f);
  unsigned r = u + 0x7fffu + ((u >> 16) & 1u);  // RNE
  return (u16)(r >> 16);
}
__device__ __forceinline__ unsigned pack2(float a, float b) {
  return (unsigned)f2bf(a) | ((unsigned)f2bf(b) << 16);
}
// truncating bf16 pack: [hi16(a) | hi16(b)<<16] in one v_perm_b32
__device__ __forceinline__ unsigned pack2t(float a, float b) {
  return __builtin_amdgcn_perm(__float_as_uint(b), __float_as_uint(a), 0x07060302u);
}
// truncate to bf16 value (numerator-consistent denominator terms)
__device__ __forceinline__ float bftrunc(float x) {
  return __uint_as_float(__float_as_uint(x) & 0xffff0000u);
}
__device__ __forceinline__ float fast_exp2(float x) {
#if __has_builtin(__builtin_amdgcn_exp2f)
  return __builtin_amdgcn_exp2f(x);  // v_exp_f32 = 2^x
#else
  return exp2f(x);
#endif
}
__device__ __forceinline__ f32x4 mfma16(ushort8v a, ushort8v b, f32x4 c) {
  return __builtin_amdgcn_mfma_f32_16x16x32_bf16(
      __builtin_bit_cast(bf16x8_t, a), __builtin_bit_cast(bf16x8_t, b), c, 0, 0, 0);
}

// ---------------- GroupNorm stats: per-(b,c) scale/shift ----------------
__global__ __launch_bounds__(256) void gn_stats_kernel(const float* __restrict__ x,
                                                       const float* __restrict__ w,
                                                       const float* __restrict__ bvec,
                                                       float* __restrict__ scl,
                                                       float* __restrict__ sh) {
  int bg = blockIdx.x;
  int bb = bg >> 5, g = bg & 31;
  size_t base = ((size_t)bb * CDIM + g * 16) * LDIM;
  const float4* x4 = (const float4*)(x + base);
  int tid = threadIdx.x;
  float sum = 0.f, ss = 0.f;
#pragma unroll
  for (int i = 0; i < 16; ++i) {
    float4 v = x4[tid + 256 * i];
    sum += v.x + v.y + v.z + v.w;
    ss += v.x * v.x + v.y * v.y + v.z * v.z + v.w * v.w;
  }
#pragma unroll
  for (int off = 32; off; off >>= 1) {
    sum += __shfl_xor(sum, off);
    ss += __shfl_xor(ss, off);
  }
  __shared__ float rs[4], rq[4];
  int lane = tid & 63, wv = tid >> 6;
  if (lane == 0) { rs[wv] = sum; rq[wv] = ss; }
  __syncthreads();
  sum = rs[0] + rs[1] + rs[2] + rs[3];
  ss = rq[0] + rq[1] + rq[2] + rq[3];
  const float inv_n = 1.f / (16.f * 1024.f);
  float mean = sum * inv_n;
  float var = ss * inv_n - mean * mean;
  float rstd = rsqrtf(var + 1e-4f);
  if (tid < 16) {
    int c = g * 16 + tid;
    float s = w[c] * rstd;
    scl[bb * CDIM + c] = s;
    sh[bb * CDIM + c] = bvec[c] - mean * s;
  }
}

// ---------------- MFMA GEMM, 128x128 tile, BK=32 ----------------
// MODE 0: merged QKV (grid.y=12): m0<512 -> Q (transposed out, scaled), <1024 -> K
//         (transposed out), else V -> v[b][c][l]. GN fused on input staging.
// MODE 2: proj -> fp32 out + bias + residual (B input = av bf16)
template <int MODE>
__global__ __launch_bounds__(256) void gemm_mfma(
    const float* __restrict__ Wg, const float* __restrict__ biasg,
    const float* __restrict__ Xf, const u16* __restrict__ Xb,
    const float* __restrict__ scl, const float* __restrict__ sh,
    const float* __restrict__ resid,
    u16* __restrict__ qo, u16* __restrict__ ko,
    u16* __restrict__ vo, float* __restrict__ fo) {
  __shared__ __align__(16) u16 Ws[128][40];  // [m][k], pad 40
  __shared__ __align__(16) u16 Xs[128][40];  // [n][k]
  int bb = blockIdx.z;
  int m0 = blockIdx.y * 128;
  int n0 = blockIdx.x * 128;
  int tid = threadIdx.x;
  int w = tid >> 6, lane = tid & 63, quad = lane >> 4, l15 = lane & 15;
  int wm = (w >> 1) * 64, wn = (w & 1) * 64;
  f32x4 acc[4][4] = {};  // QK path: [nsub][msub]; else: [msub][nsub]
  int xkb = tid >> 5, xnb = tid & 31;
  bool qkpath = (MODE == 0) && (m0 < 1024);

  for (int kk = 0; kk < 512; kk += 32) {
    float4 wv[4];
#pragma unroll
    for (int r = 0; r < 4; ++r) {
      int f = tid + 256 * r;
      wv[r] = *(const float4*)&Wg[(size_t)(m0 + (f >> 3)) * 512 + kk + (f & 7) * 4];
    }
    uint2 xw[4];
    if (MODE != 2) {
      float4 xv[4];
#pragma unroll
      for (int r = 0; r < 4; ++r) {
        int kch = kk + xkb * 4 + r;
        float s_ = scl[bb * CDIM + kch];
        float h_ = sh[bb * CDIM + kch];
        float4 t = *(const float4*)&Xf[((size_t)bb * CDIM + kch) * LDIM + n0 + xnb * 4];
        xv[r] = make_float4(t.x * s_ + h_, t.y * s_ + h_, t.z * s_ + h_, t.w * s_ + h_);
      }
#pragma unroll
      for (int j = 0; j < 4; ++j) {
        const float* p0 = (const float*)&xv[0];
        const float* p1 = (const float*)&xv[1];
        const float* p2 = (const float*)&xv[2];
        const float* p3 = (const float*)&xv[3];
        xw[j].x = pack2(p0[j], p1[j]);
        xw[j].y = pack2(p2[j], p3[j]);
      }
    } else {
      ushort4 xu[4];
#pragma unroll
      for (int r = 0; r < 4; ++r)
        xu[r] = *(const ushort4*)&Xb[((size_t)bb * CDIM + kk + xkb * 4 + r) * LDIM + n0 + xnb * 4];
#pragma unroll
      for (int j = 0; j < 4; ++j) {
        const u16* p0 = (const u16*)&xu[0];
        const u16* p1 = (const u16*)&xu[1];
        const u16* p2 = (const u16*)&xu[2];
        const u16* p3 = (const u16*)&xu[3];
        xw[j].x = (unsigned)p0[j] | ((unsigned)p1[j] << 16);
        xw[j].y = (unsigned)p2[j] | ((unsigned)p3[j] << 16);
      }
    }
    __syncthreads();
#pragma unroll
    for (int r = 0; r < 4; ++r) {
      int f = tid + 256 * r;
      uint2 u;
      u.x = pack2(wv[r].x, wv[r].y);
      u.y = pack2(wv[r].z, wv[r].w);
      *(uint2*)&Ws[f >> 3][(f & 7) * 4] = u;
    }
#pragma unroll
    for (int j = 0; j < 4; ++j) *(uint2*)&Xs[xnb * 4 + j][xkb * 4] = xw[j];
    __syncthreads();
    ushort8v af[4], bfr[4];
#pragma unroll
    for (int i = 0; i < 4; ++i) af[i] = *(const ushort8v*)&Ws[wm + i * 16 + l15][quad * 8];
#pragma unroll
    for (int i = 0; i < 4; ++i) bfr[i] = *(const ushort8v*)&Xs[wn + i * 16 + l15][quad * 8];
    if (qkpath) {
#pragma unroll
      for (int i = 0; i < 4; ++i)
#pragma unroll
        for (int j = 0; j < 4; ++j) acc[j][i] = mfma16(bfr[j], af[i], acc[j][i]);  // D[n][m]
    } else {
#pragma unroll
      for (int i = 0; i < 4; ++i)
#pragma unroll
        for (int j = 0; j < 4; ++j) acc[i][j] = mfma16(af[i], bfr[j], acc[i][j]);  // D[m][n]
    }
  }

  if (MODE == 0 && m0 < 1024) {
    bool isQ = (m0 < 512);
    // log2e folded into Q so attention can use raw v_exp_f32 (2^x)
    float qscale = isQ ? (0.125f * 1.44269504f) : 1.0f;
    u16* dst = isQ ? qo : ko;
    int cbase0 = m0 - (isQ ? 0 : 512) + wm;
#pragma unroll
    for (int i = 0; i < 4; ++i) {
      int cg = cbase0 + i * 16 + l15;
      float bv = biasg[m0 + wm + i * 16 + l15];
      int hh = cg >> 6, cl = cg & 63;
      size_t rowbase = ((size_t)(bb * 8 + hh) * 1024) * 64 + cl;
#pragma unroll
      for (int j = 0; j < 4; ++j)
#pragma unroll
        for (int r = 0; r < 4; ++r) {
          int t = n0 + wn + j * 16 + quad * 4 + r;
          dst[rowbase + (size_t)t * 64] = f2bf((acc[j][i][r] + bv) * qscale);
        }
    }
  } else if (MODE == 0) {
#pragma unroll
    for (int i = 0; i < 4; ++i)
#pragma unroll
      for (int r = 0; r < 4; ++r) {
        int m_abs = m0 + wm + i * 16 + quad * 4 + r;
        float bv = biasg[m_abs];
        int cg = m_abs - 1024;
#pragma unroll
        for (int j = 0; j < 4; ++j) {
          int n = n0 + wn + j * 16 + l15;
          vo[((size_t)bb * CDIM + cg) * LDIM + n] = f2bf(acc[i][j][r] + bv);
        }
      }
  } else {
#pragma unroll
    for (int i = 0; i < 4; ++i)
#pragma unroll
      for (int r = 0; r < 4; ++r) {
        int m_abs = m0 + wm + i * 16 + quad * 4 + r;
        float bv = biasg[m_abs];
#pragma unroll
        for (int j = 0; j < 4; ++j) {
          int n = n0 + wn + j * 16 + l15;
          size_t off = ((size_t)bb * CDIM + m_abs) * LDIM + n;
          fo[off] = acc[i][j][r] + bv + resid[off];
        }
      }
  }
}

// ---------------- Attention, MFMA, no-max softmax, depth-2 pipelined ----------------
// Grid (bh=128, tblk=8): linear id % 8 == bh % 8 -> all 8 t-blocks of one head on
// one XCD -> per-head K/V (256 KB) L2-resident (R7: FETCH 141->42 MB).
// Block: 4 waves x 32 t, one bh. TWO independent 32-s tiles per loop iteration,
// stage-batched (QK A,B -> exp/pack/write A,B -> read+PV A,B) so the serial
// chain QK->exp->ds_write->ds_read->PV is paid ~once per 64 s instead of per 32.
// K and V for both tiles prefetched one full iteration ahead (register rotate).
// Q pre-scaled by 0.125*log2e: p = v_exp_f32(score). Denominator = per-lane sums
// of TRUNCATED p (numerator-consistent), 2 shuffles at loop end. Ps wave-private
// (two buffers) -> no barriers in the loop.
__global__ __launch_bounds__(256, 3) void attn_mfma(const u16* __restrict__ qt,
                                                    const u16* __restrict__ kt,
                                                    const u16* __restrict__ vv,
                                                    u16* __restrict__ av_out) {
  __shared__ __align__(16) u16 Ps[4][2][32][40];  // per-wave double P tile, 20 KB
  int bh = blockIdx.x;
  int t0b = blockIdx.y * 128;
  int b = bh >> 3, h = bh & 7;
  int tid = threadIdx.x;
  int w = tid >> 6, lane = tid & 63, quad = lane >> 4, l15 = lane & 15;
  int t0w = t0b + w * 32;
  size_t head = (size_t)bh * 65536;  // 1024*64
  const u16* kbase = kt + head;
  const u16* vbase = vv + head;

  ushort8v qf[2][2];
#pragma unroll
  for (int ts = 0; ts < 2; ++ts)
#pragma unroll
    for (int kc = 0; kc < 2; ++kc)
      qf[ts][kc] =
          *(const ushort8v*)&qt[head + (size_t)(t0w + ts * 16 + l15) * 64 + kc * 32 + quad * 8];

  f32x4 Co[4][2] = {};
  float lacc[2] = {0.f, 0.f};

  // prefetch K and V for tiles 0 (s=0..31) and 1 (s=32..63)
  ushort8v kf[2][2][2];  // [tile][ms][kc]
  ushort8v vf[2][4];     // [tile][cs]
#pragma unroll
  for (int p = 0; p < 2; ++p) {
#pragma unroll
    for (int ms = 0; ms < 2; ++ms)
#pragma unroll
      for (int kc = 0; kc < 2; ++kc)
        kf[p][ms][kc] =
            *(const ushort8v*)&kbase[(size_t)(p * 32 + ms * 16 + l15) * 64 + kc * 32 + quad * 8];
#pragma unroll
    for (int cs = 0; cs < 4; ++cs)
      vf[p][cs] = *(const ushort8v*)&vbase[(size_t)(cs * 16 + l15) * 1024 + p * 32 + quad * 8];
  }

  for (int si = 0; si < 1024; si += 64) {
    int sn = (si + 64) & 1023;  // wrap: final prefetch reloads tile 0, unused

    // ---- stage 1: QK for both tiles (MFMA pipe) ----
    f32x4 st[2][2][2];  // [tile][ts][ms]
#pragma unroll
    for (int p = 0; p < 2; ++p)
#pragma unroll
      for (int ts = 0; ts < 2; ++ts)
#pragma unroll
        for (int ms = 0; ms < 2; ++ms) {
          f32x4 z = {};
          z = mfma16(kf[p][ms][0], qf[ts][0], z);
          st[p][ts][ms] = mfma16(kf[p][ms][1], qf[ts][1], z);
        }

    // ---- stage 2: K prefetch both tiles for next iteration ----
#pragma unroll
    for (int p = 0; p < 2; ++p)
#pragma unroll
      for (int ms = 0; ms < 2; ++ms)
#pragma unroll
        for (int kc = 0; kc < 2; ++kc)
          kf[p][ms][kc] = *(const ushort8v*)&kbase[(size_t)(sn + p * 32 + ms * 16 + l15) * 64 +
                                                   kc * 32 + quad * 8];

    // ---- stage 3: exp + pack + LDS write, tile A then tile B ----
#pragma unroll
    for (int p = 0; p < 2; ++p)
#pragma unroll
      for (int ts = 0; ts < 2; ++ts) {
        float p0 = fast_exp2(st[p][ts][0].x), p1 = fast_exp2(st[p][ts][0].y);
        float p2 = fast_exp2(st[p][ts][0].z), p3 = fast_exp2(st[p][ts][0].w);
        float p4 = fast_exp2(st[p][ts][1].x), p5 = fast_exp2(st[p][ts][1].y);
        float p6 = fast_exp2(st[p][ts][1].z), p7 = fast_exp2(st[p][ts][1].w);
        lacc[ts] += ((bftrunc(p0) + bftrunc(p1)) + (bftrunc(p2) + bftrunc(p3))) +
                    ((bftrunc(p4) + bftrunc(p5)) + (bftrunc(p6) + bftrunc(p7)));
        uint2 u0, u1;
        u0.x = pack2t(p0, p1);
        u0.y = pack2t(p2, p3);
        u1.x = pack2t(p4, p5);
        u1.y = pack2t(p6, p7);
        *(uint2*)&Ps[w][p][ts * 16 + l15][quad * 4] = u0;
        *(uint2*)&Ps[w][p][ts * 16 + l15][16 + quad * 4] = u1;
      }

    // ---- stage 4: LDS read + PV, tile A then tile B (same-wave FIFO order) ----
#pragma unroll
    for (int p = 0; p < 2; ++p) {
      ushort8v pb[2];
#pragma unroll
      for (int ts = 0; ts < 2; ++ts)
        pb[ts] = *(const ushort8v*)&Ps[w][p][ts * 16 + l15][quad * 8];
#pragma unroll
      for (int cs = 0; cs < 4; ++cs)
#pragma unroll
        for (int ts = 0; ts < 2; ++ts) Co[cs][ts] = mfma16(vf[p][cs], pb[ts], Co[cs][ts]);
    }

    // ---- stage 5: V prefetch both tiles for next iteration ----
#pragma unroll
    for (int p = 0; p < 2; ++p)
#pragma unroll
      for (int cs = 0; cs < 4; ++cs)
        vf[p][cs] =
            *(const ushort8v*)&vbase[(size_t)(cs * 16 + l15) * 1024 + sn + p * 32 + quad * 8];
  }

  // denominator: sum over quads (lanes share l15=t)
#pragma unroll
  for (int ts = 0; ts < 2; ++ts) {
    lacc[ts] += __shfl_xor(lacc[ts], 16);
    lacc[ts] += __shfl_xor(lacc[ts], 32);
  }
  float inv[2] = {1.f / lacc[0], 1.f / lacc[1]};
#pragma unroll
  for (int cs = 0; cs < 4; ++cs)
#pragma unroll
    for (int ts = 0; ts < 2; ++ts) {
      int t = t0w + ts * 16 + l15;
#pragma unroll
      for (int r = 0; r < 4; ++r) {
        int c = h * 64 + cs * 16 + quad * 4 + r;
        av_out[((size_t)b * CDIM + c) * LDIM + t] = f2bf(Co[cs][ts][r] * inv[ts]);
      }
    }
}

extern "C" void kernel_launch(void* const* d_in, const int* in_sizes, int n_in,
                              void* d_out, int out_size, void* d_ws, size_t ws_size,
                              hipStream_t stream) {
  const float* x = (const float*)d_in[0];
  const float* norm_w = (const float*)d_in[1];
  const float* norm_b = (const float*)d_in[2];
  const float* qkv_w = (const float*)d_in[3];
  const float* qkv_b = (const float*)d_in[4];
  const float* proj_w = (const float*)d_in[5];
  const float* proj_b = (const float*)d_in[6];
  float* out = (float*)d_out;

  const size_t NE = (size_t)BATCH * CDIM * LDIM;  // 8.39M
  float* scl = (float*)d_ws;
  float* sh = scl + BATCH * CDIM;
  u16* qt = (u16*)(sh + BATCH * CDIM);  // [bh][t][c] bf16
  u16* kt = qt + NE;                    // [bh][s][c] bf16
  u16* vv = kt + NE;                    // [b][c][l]  bf16
  u16* av = vv + NE;                    // [b][c][l]  bf16

  gn_stats_kernel<<<dim3(BATCH * 32), dim3(256), 0, stream>>>(x, norm_w, norm_b, scl, sh);
  gemm_mfma<0><<<dim3(8, 12, BATCH), dim3(256), 0, stream>>>(
      qkv_w, qkv_b, x, (const u16*)nullptr, scl, sh, (const float*)nullptr,
      qt, kt, vv, (float*)nullptr);
  attn_mfma<<<dim3(128, 8), dim3(256), 0, stream>>>(qt, kt, vv, av);
  gemm_mfma<2><<<dim3(8, 4, BATCH), dim3(256), 0, stream>>>(
      proj_w, proj_b, (const float*)nullptr, av, (const float*)nullptr, (const float*)nullptr,
      x, (u16*)nullptr, (u16*)nullptr, (u16*)nullptr, out);
}